// Round 1
// baseline (84.025 us; speedup 1.0000x reference)
//
#include <hip/hip_runtime.h>

// GaussianHistogram: hist[b,i,j] = sum_n exp(-pi*(u1-i)^2) * exp(-pi*(u2-j)^2) * mask
// u = (x - MIN_V)/DELTA - 0.5 ; COEF == 1.0 exactly.
//
// Two-phase gather design (v2: 4x less redundant point processing than v1):
//  Phase 1 (gh_part): block = (row-tile of 32, batch, point-chunk of 8192).
//    grid = 8 x 8 x 4 = 256 blocks (1/CU). Each block scans its 8192-point
//    chunk, accumulates taps whose ROW falls in its 32-row tile into a
//    32x256 LDS tile (ds_add_f32), then plain-stores the partial tile to ws.
//    vs v1 (8-row tiles, full 32768-pt scan): point-evals drop 8.4M -> 2.1M,
//    ds_add issues drop ~3.7x; the 6 v_exp_f32 + ~50 VALU per eval were the
//    bottleneck (kernel was issue/VALU-bound, inputs L2-resident).
//  Phase 2 (gh_reduce): out[b,r,c] = sum_z ws_partial[z][b,r,c]. 8 MB read +
//    2 MB coalesced write, fully overwrites poisoned d_out.
//
// Taps: 3x3 around round(u). Dropped taps are at distance >= 1.5 bins, weight
// <= exp(-2.25*pi) ~ 8.5e-4; expected per-cell truncation ~4e-4, far below the
// 8.6e-2 absmax threshold (fp32 noise alone measured 1.6e-2).

#define BINS   256
#define NPTS   32768
#define BATCH  8
#define TROWS  32                 // rows per tile (32 KB LDS)
#define NTILE  (BINS / TROWS)     // 8 row-tiles per batch
#define CHUNK  4                  // point chunks per batch
#define PPC    (NPTS / CHUNK)     // 8192 points per chunk
#define TILEF  (TROWS * BINS)     // 8192 floats per partial tile

static constexpr float kInvDelta = 256.0f / 1.5f;                  // 1/DELTA
static constexpr float kUAdd     = 0.25f * (256.0f / 1.5f) - 0.5f; // (x-MIN)/D - 0.5
static constexpr float kPi       = 3.14159265358979323846f;

__global__ __launch_bounds__(1024) void gh_part(
    const float* __restrict__ x1, const float* __restrict__ x2,
    const float* __restrict__ mask, float* __restrict__ ws)
{
    __shared__ float tile[TILEF];          // 32 KB
    const int tid = threadIdx.x;
    const int r0  = blockIdx.x * TROWS;    // first output row owned
    const int b   = blockIdx.y;
    const int z   = blockIdx.z;            // point chunk

    for (int i = tid; i < TILEF; i += 1024) tile[i] = 0.0f;
    __syncthreads();

    const float4* X1 = (const float4*)(x1   + b * NPTS + z * PPC);
    const float4* X2 = (const float4*)(x2   + b * NPTS + z * PPC);
    const float4* M  = (const float4*)(mask + b * NPTS + z * PPC);

#pragma unroll
    for (int it = 0; it < PPC / 4096; ++it) {   // 2 iterations, 4 points each
        const int n4 = it * 1024 + tid;
        const float4 a4 = X1[n4];
        const float4 b4 = X2[n4];
        const float4 m4 = M[n4];

        const float pv1[4] = {a4.x, a4.y, a4.z, a4.w};
        const float pv2[4] = {b4.x, b4.y, b4.z, b4.w};
        const float pm[4]  = {m4.x, m4.y, m4.z, m4.w};

#pragma unroll
        for (int k = 0; k < 4; ++k) {
            const float u1 = fmaf(pv1[k], kInvDelta, kUAdd);
            const float u2 = fmaf(pv2[k], kInvDelta, kUAdd);
            const float fi = rintf(u1);
            const float fj = rintf(u2);
            const int   i0 = (int)fi;
            int         j0 = (int)fj;
            j0 = min(254, max(1, j0));         // memory-safety (no-op for x in [0,1))
            const float t1 = u1 - fi;          // in [-0.5, 0.5]
            const float t2 = u2 - (float)j0;

            float w1[3], w2[3];
#pragma unroll
            for (int a = 0; a < 3; ++a) {
                const float d1 = t1 - (float)(a - 1);
                const float d2 = t2 - (float)(a - 1);
                w1[a] = __expf(-kPi * d1 * d1);
                w2[a] = __expf(-kPi * d2 * d2) * pm[k];
            }

            const int rbase = i0 - 1 - r0;     // tile-relative row of tap a=0
            const int cbase = j0 - 1;
#pragma unroll
            for (int a = 0; a < 3; ++a) {
                const int r = rbase + a;
                if ((unsigned)r < TROWS) {     // row owned by this block?
                    const float wa  = w1[a];
                    const int   off = r * BINS + cbase;
                    atomicAdd(&tile[off + 0], wa * w2[0]);   // ds_add_f32
                    atomicAdd(&tile[off + 1], wa * w2[1]);
                    atomicAdd(&tile[off + 2], wa * w2[2]);
                }
            }
        }
    }
    __syncthreads();

    // plain coalesced store of the partial 32x256 tile into workspace:
    // ws layout [b][tile][z][32*256] floats -> 8*8*4*8192*4B = 8 MB used.
    float4*       o4 = (float4*)(ws + (size_t)(((b * NTILE + blockIdx.x) * CHUNK + z)) * TILEF);
    const float4* t4 = (const float4*)tile;
    for (int i = tid; i < TILEF / 4; i += 1024) o4[i] = t4[i];
}

// out[b,r,c] = sum over z of ws[b][r/32][z][(r%32)*256 + c]
__global__ __launch_bounds__(1024) void gh_reduce(
    const float* __restrict__ ws, float* __restrict__ out)
{
    const int g    = blockIdx.x * 1024 + threadIdx.x;  // float4 id, 131072 total
    const int flat = g * 4;
    const int b    = flat >> 16;      // / (256*256)
    const int rem  = flat & 65535;
    const int r    = rem >> 8;
    const int c    = rem & 255;
    const int t    = r >> 5;          // row-tile
    const int rr   = r & 31;

    const float4* W = (const float4*)(ws + (size_t)((b * NTILE + t) * CHUNK) * TILEF
                                         + rr * BINS + c);
    // z-stride between partials = TILEF floats = 2048 float4
    const float4 p0 = W[0];
    const float4 p1 = W[2048];
    const float4 p2 = W[4096];
    const float4 p3 = W[6144];
    float4 s;
    s.x = (p0.x + p1.x) + (p2.x + p3.x);
    s.y = (p0.y + p1.y) + (p2.y + p3.y);
    s.z = (p0.z + p1.z) + (p2.z + p3.z);
    s.w = (p0.w + p1.w) + (p2.w + p3.w);
    ((float4*)out)[g] = s;
}

extern "C" void kernel_launch(void* const* d_in, const int* in_sizes, int n_in,
                              void* d_out, int out_size, void* d_ws, size_t ws_size,
                              hipStream_t stream) {
    const float* x1   = (const float*)d_in[0];
    const float* x2   = (const float*)d_in[1];
    const float* mask = (const float*)d_in[2];
    float*       out  = (float*)d_out;
    float*       ws   = (float*)d_ws;

    gh_part<<<dim3(NTILE, BATCH, CHUNK), 1024, 0, stream>>>(x1, x2, mask, ws);
    gh_reduce<<<dim3(BATCH * BINS * BINS / 4096), 1024, 0, stream>>>(ws, out);
}

// Round 3
// 78.261 us; speedup vs baseline: 1.0737x; 1.0737x over previous
//
#include <hip/hip_runtime.h>

// GaussianHistogram: hist[b,i,j] = sum_n exp(-pi*(u1-i)^2) * exp(-pi*(u2-j)^2) * mask
// u = (x - MIN_V)/DELTA - 0.5 ; COEF == 1.0 exactly.
//
// v4: v1 ownership structure (exact taps) + PACKED-PAIR fixed-point LDS atomics.
// Evidence: v1 (4000 ds instr/CU @ ~2.6 lanes) == v2 (1150 instr/CU @ ~8 lanes)
// == ~40us  =>  cost tracks total atomic LANE-OPS (2.36M, ~10.4 cyc each), not
// instruction count. v3 (2x2 taps) cut lane-ops 4/9 but failed absmax (0.156):
// placement error of dropped taps is too big. So: keep ALL taps, halve lane-ops
// by packing two adjacent column cells into ONE ds_add_u64 in 22.10 fixed point.
//
// Column window: 4 cells [e, e+3], e = (round(u2)-1) & ~1 (even-aligned). This
// always contains every tap at dist <= 1.5 (max dropped weight exp(-2.25*pi)
// ~ 8.5e-4, same exactness as the passing v1) plus one bonus tap. 4 cells =
// 2 u64 atomics per row; 3 exact row taps => 6 lane-ops/point (was 9).
//
// Fixed point 22.10: per-tap value w*1024 rounded-nearest (<= 1024.5). Each
// 32-bit half sums < 2^15 * 2^10 = 2^25 even if ALL 32768 points hit one cell
// -> no carry into the upper half, u64 add == two independent u32 adds. Noise
// ~1.4e-3 per cell vs 8.6e-2 threshold (v1 measured 0.0156).
//
// Ownership: block = (batch, 8-row tile); scans all 32768 pts of its batch,
// deposits owned-row taps into u64[8][128] LDS tile, converts+stores. No
// global atomics, no ws, no memset.

#define BINS   256
#define NPTS   32768
#define BATCH  8
#define TROWS  8                  // rows per tile
#define NTILE  (BINS / TROWS)     // 32 tiles -> 256 blocks, 1/CU
#define TILE64 (TROWS * BINS / 2) // 1024 u64 = 8 KB

static constexpr float kInvDelta = 256.0f / 1.5f;                  // 1/DELTA
static constexpr float kUAdd     = 0.25f * (256.0f / 1.5f) - 0.5f; // (x-MIN)/D - 0.5
static constexpr float kPi       = 3.14159265358979323846f;
static constexpr float kFix      = 1024.0f;                        // 22.10 fixed point
static constexpr float kInvFix   = 1.0f / 1024.0f;

__global__ __launch_bounds__(1024) void gh_gather(
    const float* __restrict__ x1, const float* __restrict__ x2,
    const float* __restrict__ mask, float* __restrict__ out)
{
    __shared__ unsigned long long tile[TILE64];   // 8 KB
    const int tid = threadIdx.x;
    const int r0  = blockIdx.x * TROWS;           // first output row owned
    const int b   = blockIdx.y;

    tile[tid] = 0ULL;                             // 1024 threads == TILE64
    __syncthreads();

    const float4* X1 = (const float4*)(x1   + b * NPTS);
    const float4* X2 = (const float4*)(x2   + b * NPTS);
    const float4* M  = (const float4*)(mask + b * NPTS);

#pragma unroll 2
    for (int it = 0; it < NPTS / 4096; ++it) {    // 8 iterations, 4 points each
        const int n4 = it * 1024 + tid;
        const float4 a4 = X1[n4];
        const float4 b4 = X2[n4];
        const float4 m4 = M[n4];

        const float pv1[4] = {a4.x, a4.y, a4.z, a4.w};
        const float pv2[4] = {b4.x, b4.y, b4.z, b4.w};
        const float pm[4]  = {m4.x, m4.y, m4.z, m4.w};

#pragma unroll
        for (int k = 0; k < 4; ++k) {
            const float u1 = fmaf(pv1[k], kInvDelta, kUAdd);
            const float u2 = fmaf(pv2[k], kInvDelta, kUAdd);
            const float fi = rintf(u1);
            const int   i0 = (int)fi;
            const float t1 = u1 - fi;             // in [-0.5, 0.5]

            // even-aligned 4-col window containing all taps at dist <= 1.5
            int e = (((int)rintf(u2)) - 1) & ~1;
            e = min(252, max(0, e));              // memory-safety (no-op in-spec)
            const float t2 = u2 - (float)e;       // offset of u2 from col e

            // 3 exact row weights
            float w1a[3];
#pragma unroll
            for (int a = 0; a < 3; ++a) {
                const float d = t1 - (float)(a - 1);
                w1a[a] = __expf(-kPi * d * d);
            }
            // 4 exact col weights, mask + fixed-point scale folded in
            float W2[4];
#pragma unroll
            for (int c = 0; c < 4; ++c) {
                const float d = t2 - (float)c;
                W2[c] = __expf(-kPi * d * d) * (pm[k] * kFix);
            }

            const int rbase = i0 - 1 - r0;        // tile-relative row of tap a=0
            const int pcol  = e >> 1;             // u64 column-pair index
#pragma unroll
            for (int a = 0; a < 3; ++a) {
                const int r = rbase + a;
                if ((unsigned)r < TROWS) {        // row owned by this block?
                    const float wa = w1a[a];
                    union { unsigned long long u; uint2 v; } p0, p1;
                    p0.v.x = (unsigned)fmaf(wa, W2[0], 0.5f);   // round-nearest
                    p0.v.y = (unsigned)fmaf(wa, W2[1], 0.5f);
                    p1.v.x = (unsigned)fmaf(wa, W2[2], 0.5f);
                    p1.v.y = (unsigned)fmaf(wa, W2[3], 0.5f);
                    const int idx = r * (BINS / 2) + pcol;
                    atomicAdd(&tile[idx + 0], p0.u);            // ds_add_u64
                    atomicAdd(&tile[idx + 1], p1.u);
                }
            }
        }
    }
    __syncthreads();

    // convert fixed->float and store the owned 8x256 tile (coalesced float2).
    {
        const unsigned long long v = tile[tid];
        const int r = tid >> 7;                   // /128 pairs per row
        const int p = tid & 127;
        float2 f;
        f.x = (float)(unsigned)(v & 0xffffffffULL) * kInvFix;
        f.y = (float)(unsigned)(v >> 32)           * kInvFix;
        float2* o2 = (float2*)(out + ((size_t)b * BINS + r0 + r) * BINS);
        o2[p] = f;
    }
}

extern "C" void kernel_launch(void* const* d_in, const int* in_sizes, int n_in,
                              void* d_out, int out_size, void* d_ws, size_t ws_size,
                              hipStream_t stream) {
    const float* x1   = (const float*)d_in[0];
    const float* x2   = (const float*)d_in[1];
    const float* mask = (const float*)d_in[2];
    float*       out  = (float*)d_out;

    gh_gather<<<dim3(NTILE, BATCH), 1024, 0, stream>>>(x1, x2, mask, out);
}